// Round 4
// baseline (526.915 us; speedup 1.0000x reference)
//
#include <hip/hip_runtime.h>

constexpr int T_ = 4, B_ = 32, N_ = 1024, D_ = 512, O_ = 512, OP_ = 256;
constexpr int M_ = T_ * B_ * N_;               // 131072 GEMM rows (ordered site*4 + t)
constexpr unsigned CAP = 1u * 1024 * 1024;     // repair-list capacity

// ---- ws layout (bytes) ----
constexpr size_t WS_CNT  = 0;
constexpr size_t WS_WH   = 1u << 20;
constexpr size_t WS_WM   = WS_WH + (size_t)O_ * D_ * 2;
constexpr size_t WS_XH   = 2u << 20;
constexpr size_t WS_XM   = WS_XH + (size_t)M_ * D_ * 2;
constexpr size_t WS_LIST = WS_XM + (size_t)M_ * D_ * 2;
constexpr size_t WS_NEED = WS_LIST + (size_t)CAP * 4;

typedef __attribute__((ext_vector_type(8))) short bf8;
typedef __attribute__((ext_vector_type(4))) float f4;

__device__ __forceinline__ unsigned short f2bf(float f) {
    unsigned u = __float_as_uint(f);
    unsigned r = (u + 0x7FFFu + ((u >> 16) & 1u)) >> 16;   // RNE
    return (unsigned short)r;
}
__device__ __forceinline__ float bf2f(unsigned short h) {
    return __uint_as_float(((unsigned)h) << 16);
}

// ---------------- prep: split x (with t-minor reorder), split W, reset cnt ----------------
__global__ __launch_bounds__(256) void k_prep(
    const float* __restrict__ x, const float* __restrict__ W,
    unsigned short* __restrict__ xh, unsigned short* __restrict__ xm,
    unsigned short* __restrict__ wh, unsigned short* __restrict__ wm,
    unsigned* __restrict__ cnt)
{
    if (blockIdx.x == 0 && threadIdx.x == 0) *cnt = 0u;
    const unsigned stride = gridDim.x * 256u;
    const unsigned t0 = blockIdx.x * 256u + threadIdx.x;

    for (unsigned i = t0; i < (unsigned)(M_ * 128); i += stride) {
        const unsigned row = i >> 7;
        const unsigned d4 = i & 127u;
        const unsigned t = row >> 15, b = (row >> 10) & 31u, n = row & 1023u;
        const unsigned rout = (((b << 10) | n) << 2) | t;
        const float4 v = *(const float4*)(x + ((size_t)row << 9) + (d4 << 2));
        const unsigned short h0 = f2bf(v.x), h1 = f2bf(v.y), h2 = f2bf(v.z), h3 = f2bf(v.w);
        const unsigned short m0 = f2bf(v.x - bf2f(h0)), m1 = f2bf(v.y - bf2f(h1));
        const unsigned short m2 = f2bf(v.z - bf2f(h2)), m3 = f2bf(v.w - bf2f(h3));
        *(ushort4*)(xh + ((size_t)rout << 9) + (d4 << 2)) = make_ushort4(h0, h1, h2, h3);
        *(ushort4*)(xm + ((size_t)rout << 9) + (d4 << 2)) = make_ushort4(m0, m1, m2, m3);
    }
    for (unsigned i = t0; i < (unsigned)(O_ * D_ / 4); i += stride) {
        const float4 v = *(const float4*)(W + ((size_t)i << 2));
        const unsigned short h0 = f2bf(v.x), h1 = f2bf(v.y), h2 = f2bf(v.z), h3 = f2bf(v.w);
        const unsigned short m0 = f2bf(v.x - bf2f(h0)), m1 = f2bf(v.y - bf2f(h1));
        const unsigned short m2 = f2bf(v.z - bf2f(h2)), m3 = f2bf(v.w - bf2f(h3));
        *(ushort4*)(wh + ((size_t)i << 2)) = make_ushort4(h0, h1, h2, h3);
        *(ushort4*)(wm + ((size_t)i << 2)) = make_ushort4(m0, m1, m2, m3);
    }
}

// ---------------- fast fused pass: depth-3 pipelined MFMA GEMM + BN/pool/LIF + flagging ----
// 128x128 tile, K-step 32, 16 iters, 4 LDS A-buffers (16KB each), B via pinned asm loads.
__global__ __launch_bounds__(256) void k_gemm(
    const unsigned short* __restrict__ xh, const unsigned short* __restrict__ xm,
    const unsigned short* __restrict__ wh, const unsigned short* __restrict__ wm,
    const float* __restrict__ gamma, const float* __restrict__ beta,
    const float* __restrict__ rmean, const float* __restrict__ rvar,
    float* __restrict__ out, unsigned* __restrict__ cnt, unsigned* __restrict__ list)
{
    extern __shared__ char lds[];   // 4 buffers x [term:2][row:128][64B] = 64 KiB
    const int tid  = threadIdx.x;
    const int lane = tid & 63;
    const int wid  = tid >> 6;

    const int dd = blockIdx.x;                  // 0..4095, XCD-aware swizzle
    const int w  = (dd & 7) * 512 + (dd >> 3);
    const int colblk = w & 3, rowblk = w >> 2;
    const int c0  = colblk * 128;
    const int wr0 = (wid >> 1) * 64, wc0 = (wid & 1) * 64;
    const int cbA = (lane >> 4) << 4;

    // ---- BN constants first (their loads retire before the DMA ledger starts) ----
    float invE[2], addE[2], invO[2], addO[2];
    #pragma unroll
    for (int cf = 0; cf < 2; ++cf) {
        int cE = c0 + wc0 + cf * 32 + 2 * (lane & 15);
        int cO = cE + 1;
        float ivE = gamma[cE] / sqrtf(rvar[cE] + 1e-5f);
        float ivO = gamma[cO] / sqrtf(rvar[cO] + 1e-5f);
        invE[cf] = ivE; addE[cf] = beta[cE] - rmean[cE] * ivE;
        invO[cf] = ivO; addO[cf] = beta[cO] - rmean[cO] * ivO;
    }

    // ---- staging sources: 4 loads/thread, pre-swizzled (cb ^ ((row>>1)&3)<<4) ----
    const char* gSrc[4];
    #pragma unroll
    for (int l = 0; l < 4; ++l) {
        const int flat = tid * 16 + l * 4096;
        const int term = flat >> 13;
        const int off  = flat & 8191;
        const int row  = off >> 6;
        const int cb   = off & 63;
        const char* base = (const char*)(term ? xm : xh);
        gSrc[l] = base + (size_t)(rowblk * 128 + row) * 1024 + (cb ^ (((row >> 1) & 3) << 4));
    }

    // ---- B pointers: [term*4 + cf*2 + eo] ----
    const char* bp[8];
    #pragma unroll
    for (int cf = 0; cf < 2; ++cf)
        #pragma unroll
        for (int eo = 0; eo < 2; ++eo) {
            const int c = c0 + wc0 + cf * 32 + 2 * (lane & 15) + eo;
            const size_t off = (size_t)c * 1024 + ((size_t)(lane >> 4) << 4);
            bp[0 + cf * 2 + eo] = (const char*)wh + off;
            bp[4 + cf * 2 + eo] = (const char*)wm + off;
        }

    f4 accE[4][2], accO[4][2];
    #pragma unroll
    for (int i = 0; i < 4; ++i)
        #pragma unroll
        for (int j = 0; j < 2; ++j) { accE[i][j] = (f4)0.0f; accO[i][j] = (f4)0.0f; }

    bf8 Ba[8], Bb[8];

#define SCHED __builtin_amdgcn_sched_barrier(0)

#define BLOADS(DST, J)                                                           \
    do {                                                                         \
        _Pragma("unroll") for (int q = 0; q < 8; ++q) {                          \
            asm volatile("global_load_dwordx4 %0, %1, off"                       \
                         : "=v"(DST[q])                                          \
                         : "v"(bp[q] + (J) * 64)                                 \
                         : "memory");                                            \
        }                                                                        \
    } while (0)

#define STAGE(BUF, J)                                                            \
    do {                                                                         \
        _Pragma("unroll") for (int l = 0; l < 4; ++l) {                          \
            __builtin_amdgcn_global_load_lds(                                    \
                (const __attribute__((address_space(1))) void*)(gSrc[l] +        \
                                                                (J) * 64),       \
                (__attribute__((address_space(3))) void*)(lds + (BUF) * 16384 +  \
                                                          l * 4096 +             \
                                                          wid * 1024),           \
                16, 0, 0);                                                       \
        }                                                                        \
    } while (0)

#define MFMAS(BUFI, B)                                                           \
    do {                                                                         \
        _Pragma("unroll") for (int rf = 0; rf < 4; ++rf) {                       \
            const int row = wr0 + rf * 16 + (lane & 15);                         \
            const int ao = (BUFI) * 16384 + row * 64 +                           \
                           (cbA ^ (((row >> 1) & 3) << 4));                      \
            bf8 a0 = *(const bf8*)(lds + ao);                                    \
            bf8 a1 = *(const bf8*)(lds + 8192 + ao);                             \
            _Pragma("unroll") for (int cf = 0; cf < 2; ++cf) {                   \
                accE[rf][cf] = __builtin_amdgcn_mfma_f32_16x16x32_bf16(          \
                    a0, B[0 + cf * 2], accE[rf][cf], 0, 0, 0);                   \
                accE[rf][cf] = __builtin_amdgcn_mfma_f32_16x16x32_bf16(          \
                    a0, B[4 + cf * 2], accE[rf][cf], 0, 0, 0);                   \
                accE[rf][cf] = __builtin_amdgcn_mfma_f32_16x16x32_bf16(          \
                    a1, B[0 + cf * 2], accE[rf][cf], 0, 0, 0);                   \
                accO[rf][cf] = __builtin_amdgcn_mfma_f32_16x16x32_bf16(          \
                    a0, B[1 + cf * 2], accO[rf][cf], 0, 0, 0);                   \
                accO[rf][cf] = __builtin_amdgcn_mfma_f32_16x16x32_bf16(          \
                    a0, B[5 + cf * 2], accO[rf][cf], 0, 0, 0);                   \
                accO[rf][cf] = __builtin_amdgcn_mfma_f32_16x16x32_bf16(          \
                    a1, B[1 + cf * 2], accO[rf][cf], 0, 0, 0);                   \
            }                                                                    \
        }                                                                        \
    } while (0)

// Ledger per iter j: issue B(j+1) [8], stage(j+3) [4]; vmcnt leaves
// {stage(j+2), B(j+1), stage(j+3)} in flight => retires B(j) and stage(j+1).
#define ITER(J, BC, BNX, NV)                                                     \
    do {                                                                         \
        SCHED;                                                                   \
        if ((J) < 15) BLOADS(BNX, (J) + 1);                                      \
        SCHED;                                                                   \
        if ((J) + 3 < 16) STAGE(((J) + 3) & 3, (J) + 3);                         \
        SCHED;                                                                   \
        asm volatile("s_waitcnt vmcnt(" NV ")" ::: "memory");                    \
        SCHED;                                                                   \
        __builtin_amdgcn_s_setprio(1);                                           \
        MFMAS((J) & 3, BC);                                                      \
        __builtin_amdgcn_s_setprio(0);                                           \
        SCHED;                                                                   \
        if ((J) < 15) __builtin_amdgcn_s_barrier();                              \
        SCHED;                                                                   \
    } while (0)

    // ---- prologue: B(0) + stages 0,1,2; full drain once ----
    SCHED;
    BLOADS(Ba, 0);
    STAGE(0, 0);
    STAGE(1, 1);
    STAGE(2, 2);
    SCHED;
    asm volatile("s_waitcnt vmcnt(0)" ::: "memory");
    SCHED;
    __builtin_amdgcn_s_barrier();
    SCHED;

    ITER(0,  Ba, Bb, "16");
    ITER(1,  Bb, Ba, "16");
    ITER(2,  Ba, Bb, "16");
    ITER(3,  Bb, Ba, "16");
    ITER(4,  Ba, Bb, "16");
    ITER(5,  Bb, Ba, "16");
    ITER(6,  Ba, Bb, "16");
    ITER(7,  Bb, Ba, "16");
    ITER(8,  Ba, Bb, "16");
    ITER(9,  Bb, Ba, "16");
    ITER(10, Ba, Bb, "16");
    ITER(11, Bb, Ba, "16");
    ITER(12, Ba, Bb, "16");
    ITER(13, Bb, Ba, "12");
    ITER(14, Ba, Bb, "8");
    ITER(15, Bb, Ba, "0");

#undef ITER
#undef MFMAS
#undef STAGE
#undef BLOADS
#undef SCHED

    // ---- epilogue: BN -> pool -> LIF, flag near-threshold pipelines ----
    #pragma unroll
    for (int rf = 0; rf < 4; ++rf) {
        const int site = rowblk * 32 + (wid >> 1) * 16 + rf * 4 + (lane >> 4);
        const int bI = site >> 10, nI = site & 1023;
        #pragma unroll
        for (int cf = 0; cf < 2; ++cf) {
            const int op = ((c0 + wc0 + cf * 32) >> 1) + (lane & 15);
            float v = 0.0f;
            bool flg = false;
            #pragma unroll
            for (int t = 0; t < 4; ++t) {
                float hE = accE[rf][cf][t] * invE[cf] + addE[cf];
                float hO = accO[rf][cf][t] * invO[cf] + addO[cf];
                float m = fmaxf(hE, hO);
                v = (v + m) * 0.5f;
                float dv = v - 1.0f;
                bool sp = dv >= 0.0f;
                out[(((size_t)t * 32 + bI) * 1024 + nI) * 256 + op] = sp ? 1.0f : 0.0f;
                flg |= (fabsf(dv) < 2e-4f);
                if (sp) v = 0.0f;
            }
            if (flg) {
                unsigned idx = atomicAdd(cnt, 1u);
                if (idx < CAP) list[idx] = ((unsigned)site << 8) | (unsigned)op;
            }
        }
    }
}

// ---------------- exact f64 repair of flagged pipelines ----------------
__global__ __launch_bounds__(256) void k_repair(
    const float* __restrict__ x, const float* __restrict__ W,
    const float* __restrict__ gamma, const float* __restrict__ beta,
    const float* __restrict__ rmean, const float* __restrict__ rvar,
    float* __restrict__ out, const unsigned* __restrict__ cnt,
    const unsigned* __restrict__ list)
{
    unsigned count = *cnt;
    if (count > CAP) count = CAP;
    for (unsigned j = blockIdx.x * 256 + threadIdx.x; j < count; j += 256u * 256u) {
        const unsigned e = list[j];
        const int op = e & 255;
        const int site = e >> 8;
        const int bI = site >> 10, nI = site & 1023;

        double h[4][2];
        #pragma unroll
        for (int p = 0; p < 2; ++p) {
            const int c = 2 * op + p;
            const float* Wr = W + (size_t)c * D_;
            #pragma unroll
            for (int t = 0; t < 4; ++t) {
                const float* xr = x + (((size_t)t * 32 + bI) * 1024 + nI) * D_;
                double s0 = 0, s1 = 0, s2 = 0, s3 = 0;
                for (int d = 0; d < D_; d += 4) {
                    float4 xv = *(const float4*)(xr + d);
                    float4 wv = *(const float4*)(Wr + d);
                    s0 = fma((double)xv.x, (double)wv.x, s0);
                    s1 = fma((double)xv.y, (double)wv.y, s1);
                    s2 = fma((double)xv.z, (double)wv.z, s2);
                    s3 = fma((double)xv.w, (double)wv.w, s3);
                }
                h[t][p] = (s0 + s1) + (s2 + s3);
            }
        }
        double iv[2], ad[2];
        #pragma unroll
        for (int p = 0; p < 2; ++p) {
            const int c = 2 * op + p;
            iv[p] = (double)gamma[c] / sqrt((double)rvar[c] + 1e-5);
            ad[p] = (double)beta[c] - (double)rmean[c] * iv[p];
        }
        double v = 0.0;
        #pragma unroll
        for (int t = 0; t < 4; ++t) {
            double h0 = h[t][0] * iv[0] + ad[0];
            double h1 = h[t][1] * iv[1] + ad[1];
            double m = fmax(h0, h1);
            v = (v + m) * 0.5;
            const bool sp = (v >= 1.0);
            out[(((size_t)t * 32 + bI) * 1024 + nI) * 256 + op] = sp ? 1.0f : 0.0f;
            if (sp) v = 0.0;
        }
    }
}

// ---------------- fallback (round-1 exact f64 kernel) ----------------
constexpr int FB_SITES = 32, FB_ROWS = 128, FB_BN = 64, FB_BK = 16;

__global__ __launch_bounds__(256)
void snn_fused_f64(const float* __restrict__ x, const float* __restrict__ W,
                   const float* __restrict__ gamma, const float* __restrict__ beta,
                   const float* __restrict__ rmean, const float* __restrict__ rvar,
                   float* __restrict__ out)
{
    __shared__ float As[FB_BK][FB_ROWS];
    __shared__ float Bs[FB_BK][FB_BN];
    const int tid = threadIdx.x;
    const int tx = tid & 15, ty = tid >> 4;
    const int c0 = blockIdx.x * FB_BN;
    const int site_base = blockIdx.y * FB_SITES;
    const int b = site_base / N_, n0 = site_base % N_;
    const int lrow = tid >> 1, lk = (tid & 1) * 8;
    const int s_l = lrow >> 2, t_l = lrow & 3;
    const float* xrow = x + (size_t)((t_l * B_ + b) * N_ + (n0 + s_l)) * D_ + lk;
    const int wc = tid & 63, wk = (tid >> 6) * 4;
    const float* wrow = W + (size_t)(c0 + wc) * D_ + wk;
    double acc[8][4];
    #pragma unroll
    for (int i = 0; i < 8; ++i)
        #pragma unroll
        for (int j = 0; j < 4; ++j) acc[i][j] = 0.0;
    for (int k0 = 0; k0 < D_; k0 += FB_BK) {
        const float4 a0 = *(const float4*)(xrow + k0);
        const float4 a1 = *(const float4*)(xrow + k0 + 4);
        const float4 w4 = *(const float4*)(wrow + k0);
        As[lk + 0][lrow] = a0.x; As[lk + 1][lrow] = a0.y; As[lk + 2][lrow] = a0.z; As[lk + 3][lrow] = a0.w;
        As[lk + 4][lrow] = a1.x; As[lk + 5][lrow] = a1.y; As[lk + 6][lrow] = a1.z; As[lk + 7][lrow] = a1.w;
        Bs[wk + 0][wc] = w4.x; Bs[wk + 1][wc] = w4.y; Bs[wk + 2][wc] = w4.z; Bs[wk + 3][wc] = w4.w;
        __syncthreads();
        #pragma unroll
        for (int k = 0; k < FB_BK; ++k) {
            const float4 af0 = *(const float4*)&As[k][ty * 8];
            const float4 af1 = *(const float4*)&As[k][ty * 8 + 4];
            const float4 bf = *(const float4*)&Bs[k][tx * 4];
            const double ad[8] = {(double)af0.x, (double)af0.y, (double)af0.z, (double)af0.w,
                                  (double)af1.x, (double)af1.y, (double)af1.z, (double)af1.w};
            const double bd[4] = {(double)bf.x, (double)bf.y, (double)bf.z, (double)bf.w};
            #pragma unroll
            for (int i = 0; i < 8; ++i)
                #pragma unroll
                for (int j = 0; j < 4; ++j) acc[i][j] = fma(ad[i], bd[j], acc[i][j]);
        }
        __syncthreads();
    }
    double invd[4], addd[4];
    #pragma unroll
    for (int j = 0; j < 4; ++j) {
        const int c = c0 + tx * 4 + j;
        const double ivv = (double)gamma[c] / sqrt((double)rvar[c] + 1e-5);
        invd[j] = ivv; addd[j] = (double)beta[c] - (double)rmean[c] * ivv;
    }
    #pragma unroll
    for (int si = 0; si < 2; ++si) {
        const int n = n0 + ty * 2 + si;
        #pragma unroll
        for (int p = 0; p < 2; ++p) {
            const int op = (c0 >> 1) + tx * 2 + p;
            double v = 0.0;
            #pragma unroll
            for (int t = 0; t < 4; ++t) {
                const int i = si * 4 + t;
                const double h0 = acc[i][2 * p] * invd[2 * p] + addd[2 * p];
                const double h1 = acc[i][2 * p + 1] * invd[2 * p + 1] + addd[2 * p + 1];
                const double m = fmax(h0, h1);
                v = v + (m - v) * 0.5;
                const bool sp = (v >= 1.0);
                out[((size_t)(t * B_ + b) * N_ + n) * OP_ + op] = sp ? 1.0f : 0.0f;
                if (sp) v = 0.0;
            }
        }
    }
}

extern "C" void kernel_launch(void* const* d_in, const int* in_sizes, int n_in,
                              void* d_out, int out_size, void* d_ws, size_t ws_size,
                              hipStream_t stream)
{
    const float* x     = (const float*)d_in[0];
    const float* W     = (const float*)d_in[1];
    const float* gamma = (const float*)d_in[2];
    const float* beta  = (const float*)d_in[3];
    const float* rmean = (const float*)d_in[4];
    const float* rvar  = (const float*)d_in[5];
    float* out = (float*)d_out;

    if (ws_size < WS_NEED) {
        dim3 grid(O_ / FB_BN, (B_ * N_) / FB_SITES);
        snn_fused_f64<<<grid, dim3(256), 0, stream>>>(x, W, gamma, beta, rmean, rvar, out);
        return;
    }

    char* ws = (char*)d_ws;
    unsigned* cnt = (unsigned*)(ws + WS_CNT);
    unsigned short* wh = (unsigned short*)(ws + WS_WH);
    unsigned short* wm = (unsigned short*)(ws + WS_WM);
    unsigned short* xh = (unsigned short*)(ws + WS_XH);
    unsigned short* xm = (unsigned short*)(ws + WS_XM);
    unsigned* list = (unsigned*)(ws + WS_LIST);

    k_prep<<<8192, 256, 0, stream>>>(x, W, xh, xm, wh, wm, cnt);
    k_gemm<<<4096, 256, 65536, stream>>>(xh, xm, wh, wm, gamma, beta, rmean, rvar, out, cnt, list);
    k_repair<<<256, 256, 0, stream>>>(x, W, gamma, beta, rmean, rvar, out, cnt, list);
}

// Round 5
// 330.416 us; speedup vs baseline: 1.5947x; 1.5947x over previous
//
#include <hip/hip_runtime.h>

constexpr int T_ = 4, B_ = 32, N_ = 1024, D_ = 512, O_ = 512, OP_ = 256;
constexpr int M_ = T_ * B_ * N_;
constexpr unsigned CAP = 1u * 1024 * 1024;

// ---- ws layout (bytes) ----
constexpr size_t WS_CNT  = 0;
constexpr size_t WS_WP   = 1u << 20;                  // 1 MiB fragment-ordered W (hi+lo)
constexpr size_t WS_LIST = WS_WP + (1u << 20);
constexpr size_t WS_NEED = WS_LIST + (size_t)CAP * 4;

typedef __attribute__((ext_vector_type(8))) short bf8;
typedef __attribute__((ext_vector_type(4))) float f4;

__device__ __forceinline__ unsigned cvtpk(float x0, float x1) {
    unsigned r;
    asm("v_cvt_pk_bf16_f32 %0, %1, %2" : "=v"(r) : "v"(x0), "v"(x1));
    return r;
}
__device__ __forceinline__ float hi_lo_f(unsigned u) { return __uint_as_float(u << 16); }
__device__ __forceinline__ float hi_hi_f(unsigned u) { return __uint_as_float(u & 0xffff0000u); }

// ---------------- W prep: fragment-ordered hi/lo split + cnt reset ----------------
// wp chunk id c = [panel:8][j:16][q:8][lane:64], 16B each.
// col = colblk*128 + half*64 + cf*32 + 2*(lane&15) + eo ; k = j*32 + (lane>>4)*8 .. +8
__global__ __launch_bounds__(256) void k_wprep(const float* __restrict__ W,
                                               unsigned short* __restrict__ wp,
                                               unsigned* __restrict__ cnt)
{
    if (blockIdx.x == 0 && threadIdx.x == 0) *cnt = 0u;
    const int c = blockIdx.x * 256 + threadIdx.x;      // 0..65535
    const int lane = c & 63, q = (c >> 6) & 7, j = (c >> 9) & 15, panel = c >> 13;
    const int colblk = panel >> 1, half = panel & 1;
    const int term = q >> 2, cf = (q >> 1) & 1, eo = q & 1;
    const int col = colblk * 128 + half * 64 + cf * 32 + 2 * (lane & 15) + eo;
    const int k0 = j * 32 + (lane >> 4) * 8;
    const float* src = W + (size_t)col * 512 + k0;
    const float4 v0 = *(const float4*)(src);
    const float4 v1 = *(const float4*)(src + 4);
    const float xs[8] = {v0.x, v0.y, v0.z, v0.w, v1.x, v1.y, v1.z, v1.w};
    unsigned o[4];
    #pragma unroll
    for (int p = 0; p < 4; ++p) {
        const unsigned hi = cvtpk(xs[2 * p], xs[2 * p + 1]);
        if (term == 0) {
            o[p] = hi;
        } else {
            const float l0 = xs[2 * p] - hi_lo_f(hi);
            const float l1 = xs[2 * p + 1] - hi_hi_f(hi);
            o[p] = cvtpk(l0, l1);
        }
    }
    *(uint4*)(wp + (size_t)c * 8) = make_uint4(o[0], o[1], o[2], o[3]);
}

// ---------------- fused: reg-staged A split + coalesced B + MFMA + BN/pool/LIF + flag ----
__global__ __launch_bounds__(256) void k_gemm(
    const float* __restrict__ x, const unsigned short* __restrict__ wp,
    const float* __restrict__ gamma, const float* __restrict__ beta,
    const float* __restrict__ rmean, const float* __restrict__ rvar,
    float* __restrict__ out, unsigned* __restrict__ cnt, unsigned* __restrict__ list)
{
    extern __shared__ char lds[];   // 2 bufs x [term:2][row:128][64B] = 32 KiB
    const int tid  = threadIdx.x;
    const int lane = tid & 63;
    const int wid  = tid >> 6;

    const int dd = blockIdx.x;                  // XCD-aware swizzle
    const int w  = (dd & 7) * 512 + (dd >> 3);
    const int colblk = w & 3, rowblk = w >> 2;
    const int c0  = colblk * 128;
    const int wr0 = (wid >> 1) * 64, wc0 = (wid & 1) * 64;
    const int cbA = (lane >> 4) << 4;

    // ---- BN constants ----
    float invE[2], addE[2], invO[2], addO[2];
    #pragma unroll
    for (int cf = 0; cf < 2; ++cf) {
        int cE = c0 + wc0 + cf * 32 + 2 * (lane & 15);
        int cO = cE + 1;
        float ivE = gamma[cE] / sqrtf(rvar[cE] + 1e-5f);
        float ivO = gamma[cO] / sqrtf(rvar[cO] + 1e-5f);
        invE[cf] = ivE; addE[cf] = beta[cE] - rmean[cE] * ivE;
        invO[cf] = ivO; addO[cf] = beta[cO] - rmean[cO] * ivO;
    }

    // ---- A staging map: thread -> (row, kh); rows are t-interleaved (row = s*4+t) ----
    const int arow = tid >> 1;          // 0..127
    const int kh   = tid & 1;           // 16-float half of the 32-float K-step
    const int at   = arow & 3;
    const int asite = rowblk * 32 + (arow >> 2);
    const char* gxA = (const char*)x + ((size_t)(at * 32768 + asite)) * 2048 + kh * 64;
    const int swzA = ((arow >> 1) & 3) << 4;
    const int wb0 = arow * 64 + ((kh * 32 + 0) ^ swzA);
    const int wb1 = arow * 64 + ((kh * 32 + 16) ^ swzA);

    // ---- B: fragment-ordered panel base ----
    const int panel = colblk * 2 + (wid & 1);
    const char* bpB = (const char*)wp + ((size_t)panel << 17) + lane * 16;

    f4 accE[4][2], accO[4][2];
    #pragma unroll
    for (int i = 0; i < 4; ++i)
        #pragma unroll
        for (int j = 0; j < 2; ++j) { accE[i][j] = (f4)0.0f; accO[i][j] = (f4)0.0f; }

    float4 Aa[4], Ab[4];
    bf8 Ba[8], Bb[8];

#define SCHED __builtin_amdgcn_sched_barrier(0)

#define ALOADS(DST, K)                                                           \
    do {                                                                         \
        _Pragma("unroll") for (int i = 0; i < 4; ++i) {                          \
            asm volatile("global_load_dwordx4 %0, %1, off"                       \
                         : "=v"(DST[i])                                          \
                         : "v"(gxA + (K) * 128 + i * 16)                         \
                         : "memory");                                            \
        }                                                                        \
    } while (0)

#define BLOADS(DST, K)                                                           \
    do {                                                                         \
        _Pragma("unroll") for (int q = 0; q < 8; ++q) {                          \
            asm volatile("global_load_dwordx4 %0, %1, off"                       \
                         : "=v"(DST[q])                                          \
                         : "v"(bpB + ((K) * 8 + q) * 1024)                       \
                         : "memory");                                            \
        }                                                                        \
    } while (0)

// convert 16 f32 (already retired into R) -> hi/lo bf16, swizzled LDS write
#define CONVWRITE(R, BUF)                                                        \
    do {                                                                         \
        _Pragma("unroll") for (int cc = 0; cc < 2; ++cc) {                       \
            const float4 v0 = R[cc * 2], v1 = R[cc * 2 + 1];                     \
            const unsigned h0 = cvtpk(v0.x, v0.y), h1 = cvtpk(v0.z, v0.w);       \
            const unsigned h2 = cvtpk(v1.x, v1.y), h3 = cvtpk(v1.z, v1.w);       \
            const unsigned l0 = cvtpk(v0.x - hi_lo_f(h0), v0.y - hi_hi_f(h0));   \
            const unsigned l1 = cvtpk(v0.z - hi_lo_f(h1), v0.w - hi_hi_f(h1));   \
            const unsigned l2 = cvtpk(v1.x - hi_lo_f(h2), v1.y - hi_hi_f(h2));   \
            const unsigned l3 = cvtpk(v1.z - hi_lo_f(h3), v1.w - hi_hi_f(h3));   \
            const int wb = cc ? wb1 : wb0;                                       \
            *(uint4*)(lds + (BUF) * 16384 + wb) = make_uint4(h0, h1, h2, h3);    \
            *(uint4*)(lds + (BUF) * 16384 + 8192 + wb) =                         \
                make_uint4(l0, l1, l2, l3);                                      \
        }                                                                        \
    } while (0)

#define MFMAS(BUFI, B)                                                           \
    do {                                                                         \
        _Pragma("unroll") for (int rf = 0; rf < 4; ++rf) {                       \
            const int row = wr0 + rf * 16 + (lane & 15);                         \
            const int ao = (BUFI) * 16384 + row * 64 +                           \
                           (cbA ^ (((row >> 1) & 3) << 4));                      \
            bf8 a0 = *(const bf8*)(lds + ao);                                    \
            bf8 a1 = *(const bf8*)(lds + 8192 + ao);                             \
            _Pragma("unroll") for (int cf = 0; cf < 2; ++cf) {                   \
                accE[rf][cf] = __builtin_amdgcn_mfma_f32_16x16x32_bf16(          \
                    a0, B[0 + cf * 2], accE[rf][cf], 0, 0, 0);                   \
                accE[rf][cf] = __builtin_amdgcn_mfma_f32_16x16x32_bf16(          \
                    a0, B[4 + cf * 2], accE[rf][cf], 0, 0, 0);                   \
                accE[rf][cf] = __builtin_amdgcn_mfma_f32_16x16x32_bf16(          \
                    a1, B[0 + cf * 2], accE[rf][cf], 0, 0, 0);                   \
                accO[rf][cf] = __builtin_amdgcn_mfma_f32_16x16x32_bf16(          \
                    a0, B[1 + cf * 2], accO[rf][cf], 0, 0, 0);                   \
                accO[rf][cf] = __builtin_amdgcn_mfma_f32_16x16x32_bf16(          \
                    a0, B[5 + cf * 2], accO[rf][cf], 0, 0, 0);                   \
                accO[rf][cf] = __builtin_amdgcn_mfma_f32_16x16x32_bf16(          \
                    a1, B[1 + cf * 2], accO[rf][cf], 0, 0, 0);                   \
            }                                                                    \
        }                                                                        \
    } while (0)

// Ledger invariant at iter J start: outstanding = {A(J+1):4, B(J):8}.
// Issue A(J+2):4, B(J+1):8 -> 24; vmcnt(12) retires exactly A(J+1)+B(J).
#define ITER(J, ATGT, ACVT, BC, BN2, NV)                                         \
    do {                                                                         \
        SCHED;                                                                   \
        if ((J) + 2 < 16) ALOADS(ATGT, (J) + 2);                                 \
        SCHED;                                                                   \
        if ((J) + 1 < 16) BLOADS(BN2, (J) + 1);                                  \
        SCHED;                                                                   \
        asm volatile("s_waitcnt vmcnt(" NV ")" ::: "memory");                    \
        SCHED;                                                                   \
        if ((J) + 1 < 16) CONVWRITE(ACVT, ((J) + 1) & 1);                        \
        SCHED;                                                                   \
        __builtin_amdgcn_s_setprio(1);                                           \
        MFMAS((J) & 1, BC);                                                      \
        __builtin_amdgcn_s_setprio(0);                                           \
        SCHED;                                                                   \
        asm volatile("s_waitcnt lgkmcnt(0)" ::: "memory");                       \
        if ((J) < 15) __builtin_amdgcn_s_barrier();                              \
        SCHED;                                                                   \
    } while (0)

    // ---- prologue: A(0)->Aa, A(1)->Ab, B(0)->Ba; retire A(0); write buf0 ----
    SCHED;
    ALOADS(Aa, 0);
    ALOADS(Ab, 1);
    BLOADS(Ba, 0);
    SCHED;
    asm volatile("s_waitcnt vmcnt(12)" ::: "memory");
    SCHED;
    CONVWRITE(Aa, 0);
    SCHED;
    asm volatile("s_waitcnt lgkmcnt(0)" ::: "memory");
    __builtin_amdgcn_s_barrier();
    SCHED;

    ITER(0,  Aa, Ab, Ba, Bb, "12");
    ITER(1,  Ab, Aa, Bb, Ba, "12");
    ITER(2,  Aa, Ab, Ba, Bb, "12");
    ITER(3,  Ab, Aa, Bb, Ba, "12");
    ITER(4,  Aa, Ab, Ba, Bb, "12");
    ITER(5,  Ab, Aa, Bb, Ba, "12");
    ITER(6,  Aa, Ab, Ba, Bb, "12");
    ITER(7,  Ab, Aa, Bb, Ba, "12");
    ITER(8,  Aa, Ab, Ba, Bb, "12");
    ITER(9,  Ab, Aa, Bb, Ba, "12");
    ITER(10, Aa, Ab, Ba, Bb, "12");
    ITER(11, Ab, Aa, Bb, Ba, "12");
    ITER(12, Aa, Ab, Ba, Bb, "12");
    ITER(13, Ab, Aa, Bb, Ba, "12");
    ITER(14, Aa, Ab, Ba, Bb, "8");
    ITER(15, Ab, Aa, Bb, Ba, "0");

#undef ITER
#undef MFMAS
#undef CONVWRITE
#undef BLOADS
#undef ALOADS
#undef SCHED

    // ---- epilogue: BN -> pool -> LIF, flag near-threshold pipelines ----
    #pragma unroll
    for (int rf = 0; rf < 4; ++rf) {
        const int site = rowblk * 32 + (wid >> 1) * 16 + rf * 4 + (lane >> 4);
        const int bI = site >> 10, nI = site & 1023;
        #pragma unroll
        for (int cf = 0; cf < 2; ++cf) {
            const int op = ((c0 + wc0 + cf * 32) >> 1) + (lane & 15);
            float v = 0.0f;
            bool flg = false;
            #pragma unroll
            for (int t = 0; t < 4; ++t) {
                float hE = accE[rf][cf][t] * invE[cf] + addE[cf];
                float hO = accO[rf][cf][t] * invO[cf] + addO[cf];
                float m = fmaxf(hE, hO);
                v = (v + m) * 0.5f;
                float dv = v - 1.0f;
                bool sp = dv >= 0.0f;
                out[(((size_t)t * 32 + bI) * 1024 + nI) * 256 + op] = sp ? 1.0f : 0.0f;
                flg |= (fabsf(dv) < 2e-4f);
                if (sp) v = 0.0f;
            }
            if (flg) {
                unsigned idx = atomicAdd(cnt, 1u);
                if (idx < CAP) list[idx] = ((unsigned)site << 8) | (unsigned)op;
            }
        }
    }
}

// ---------------- exact f64 repair of flagged pipelines ----------------
__global__ __launch_bounds__(256) void k_repair(
    const float* __restrict__ x, const float* __restrict__ W,
    const float* __restrict__ gamma, const float* __restrict__ beta,
    const float* __restrict__ rmean, const float* __restrict__ rvar,
    float* __restrict__ out, const unsigned* __restrict__ cnt,
    const unsigned* __restrict__ list)
{
    unsigned count = *cnt;
    if (count > CAP) count = CAP;
    for (unsigned j = blockIdx.x * 256 + threadIdx.x; j < count; j += 256u * 256u) {
        const unsigned e = list[j];
        const int op = e & 255;
        const int site = e >> 8;
        const int bI = site >> 10, nI = site & 1023;

        double h[4][2];
        #pragma unroll
        for (int p = 0; p < 2; ++p) {
            const int c = 2 * op + p;
            const float* Wr = W + (size_t)c * D_;
            #pragma unroll
            for (int t = 0; t < 4; ++t) {
                const float* xr = x + (((size_t)t * 32 + bI) * 1024 + nI) * D_;
                double s0 = 0, s1 = 0, s2 = 0, s3 = 0;
                for (int d = 0; d < D_; d += 4) {
                    float4 xv = *(const float4*)(xr + d);
                    float4 wv = *(const float4*)(Wr + d);
                    s0 = fma((double)xv.x, (double)wv.x, s0);
                    s1 = fma((double)xv.y, (double)wv.y, s1);
                    s2 = fma((double)xv.z, (double)wv.z, s2);
                    s3 = fma((double)xv.w, (double)wv.w, s3);
                }
                h[t][p] = (s0 + s1) + (s2 + s3);
            }
        }
        double iv[2], ad[2];
        #pragma unroll
        for (int p = 0; p < 2; ++p) {
            const int c = 2 * op + p;
            iv[p] = (double)gamma[c] / sqrt((double)rvar[c] + 1e-5);
            ad[p] = (double)beta[c] - (double)rmean[c] * iv[p];
        }
        double v = 0.0;
        #pragma unroll
        for (int t = 0; t < 4; ++t) {
            double h0 = h[t][0] * iv[0] + ad[0];
            double h1 = h[t][1] * iv[1] + ad[1];
            double m = fmax(h0, h1);
            v = (v + m) * 0.5;
            const bool sp = (v >= 1.0);
            out[(((size_t)t * 32 + bI) * 1024 + nI) * 256 + op] = sp ? 1.0f : 0.0f;
            if (sp) v = 0.0;
        }
    }
}

// ---------------- fallback (round-1 exact f64 kernel) ----------------
constexpr int FB_SITES = 32, FB_ROWS = 128, FB_BN = 64, FB_BK = 16;

__global__ __launch_bounds__(256)
void snn_fused_f64(const float* __restrict__ x, const float* __restrict__ W,
                   const float* __restrict__ gamma, const float* __restrict__ beta,
                   const float* __restrict__ rmean, const float* __restrict__ rvar,
                   float* __restrict__ out)
{
    __shared__ float As[FB_BK][FB_ROWS];
    __shared__ float Bs[FB_BK][FB_BN];
    const int tid = threadIdx.x;
    const int tx = tid & 15, ty = tid >> 4;
    const int c0 = blockIdx.x * FB_BN;
    const int site_base = blockIdx.y * FB_SITES;
    const int b = site_base / N_, n0 = site_base % N_;
    const int lrow = tid >> 1, lk = (tid & 1) * 8;
    const int s_l = lrow >> 2, t_l = lrow & 3;
    const float* xrow = x + (size_t)((t_l * B_ + b) * N_ + (n0 + s_l)) * D_ + lk;
    const int wc = tid & 63, wk = (tid >> 6) * 4;
    const float* wrow = W + (size_t)(c0 + wc) * D_ + wk;
    double acc[8][4];
    #pragma unroll
    for (int i = 0; i < 8; ++i)
        #pragma unroll
        for (int j = 0; j < 4; ++j) acc[i][j] = 0.0;
    for (int k0 = 0; k0 < D_; k0 += FB_BK) {
        const float4 a0 = *(const float4*)(xrow + k0);
        const float4 a1 = *(const float4*)(xrow + k0 + 4);
        const float4 w4 = *(const float4*)(wrow + k0);
        As[lk + 0][lrow] = a0.x; As[lk + 1][lrow] = a0.y; As[lk + 2][lrow] = a0.z; As[lk + 3][lrow] = a0.w;
        As[lk + 4][lrow] = a1.x; As[lk + 5][lrow] = a1.y; As[lk + 6][lrow] = a1.z; As[lk + 7][lrow] = a1.w;
        Bs[wk + 0][wc] = w4.x; Bs[wk + 1][wc] = w4.y; Bs[wk + 2][wc] = w4.z; Bs[wk + 3][wc] = w4.w;
        __syncthreads();
        #pragma unroll
        for (int k = 0; k < FB_BK; ++k) {
            const float4 af0 = *(const float4*)&As[k][ty * 8];
            const float4 af1 = *(const float4*)&As[k][ty * 8 + 4];
            const float4 bf = *(const float4*)&Bs[k][tx * 4];
            const double ad[8] = {(double)af0.x, (double)af0.y, (double)af0.z, (double)af0.w,
                                  (double)af1.x, (double)af1.y, (double)af1.z, (double)af1.w};
            const double bd[4] = {(double)bf.x, (double)bf.y, (double)bf.z, (double)bf.w};
            #pragma unroll
            for (int i = 0; i < 8; ++i)
                #pragma unroll
                for (int j = 0; j < 4; ++j) acc[i][j] = fma(ad[i], bd[j], acc[i][j]);
        }
        __syncthreads();
    }
    double invd[4], addd[4];
    #pragma unroll
    for (int j = 0; j < 4; ++j) {
        const int c = c0 + tx * 4 + j;
        const double ivv = (double)gamma[c] / sqrt((double)rvar[c] + 1e-5);
        invd[j] = ivv; addd[j] = (double)beta[c] - (double)rmean[c] * ivv;
    }
    #pragma unroll
    for (int si = 0; si < 2; ++si) {
        const int n = n0 + ty * 2 + si;
        #pragma unroll
        for (int p = 0; p < 2; ++p) {
            const int op = (c0 >> 1) + tx * 2 + p;
            double v = 0.0;
            #pragma unroll
            for (int t = 0; t < 4; ++t) {
                const int i = si * 4 + t;
                const double h0 = acc[i][2 * p] * invd[2 * p] + addd[2 * p];
                const double h1 = acc[i][2 * p + 1] * invd[2 * p + 1] + addd[2 * p + 1];
                const double m = fmax(h0, h1);
                v = v + (m - v) * 0.5;
                const bool sp = (v >= 1.0);
                out[((size_t)(t * B_ + b) * N_ + n) * OP_ + op] = sp ? 1.0f : 0.0f;
                if (sp) v = 0.0;
            }
        }
    }
}

extern "C" void kernel_launch(void* const* d_in, const int* in_sizes, int n_in,
                              void* d_out, int out_size, void* d_ws, size_t ws_size,
                              hipStream_t stream)
{
    const float* x     = (const float*)d_in[0];
    const float* W     = (const float*)d_in[1];
    const float* gamma = (const float*)d_in[2];
    const float* beta  = (const float*)d_in[3];
    const float* rmean = (const float*)d_in[4];
    const float* rvar  = (const float*)d_in[5];
    float* out = (float*)d_out;

    if (ws_size < WS_NEED) {
        dim3 grid(O_ / FB_BN, (B_ * N_) / FB_SITES);
        snn_fused_f64<<<grid, dim3(256), 0, stream>>>(x, W, gamma, beta, rmean, rvar, out);
        return;
    }

    char* ws = (char*)d_ws;
    unsigned* cnt = (unsigned*)(ws + WS_CNT);
    unsigned short* wp = (unsigned short*)(ws + WS_WP);
    unsigned* list = (unsigned*)(ws + WS_LIST);

    k_wprep<<<256, 256, 0, stream>>>(W, wp, cnt);
    k_gemm<<<4096, 256, 32768, stream>>>(x, wp, gamma, beta, rmean, rvar, out, cnt, list);
    k_repair<<<256, 256, 0, stream>>>(x, W, gamma, beta, rmean, rvar, out, cnt, list);
}